// Round 12
// baseline (435.037 us; speedup 1.0000x reference)
//
#include <hip/hip_runtime.h>
#include <hip/hip_cooperative_groups.h>

namespace cg = cooperative_groups;

#define N_USERS 100000
#define N_ITEMS 50000
#define N_NODES 150000   // N_USERS + N_ITEMS
#define NNZ     1200000
#define DIM     64
#define BATCH   16384
#define MAXDEG  64       // max degree over needed rows ~30 at Pois(8); writes clamped
#define NBLK    1024     // cooperative grid: 4 blocks/CU * 256 CUs
#define NTHR    256

// ws layout:
//   rowid : N_NODES uint   (init 0xFFFFFFFF in-kernel)
//   cnt   : 2*BATCH uint   (zeroed in-kernel)
//   pairs : 2*BATCH*MAXDEG uint2 {col, val-bits} (written before read)

__device__ __forceinline__ const float* emb_ptr(const float* ue, const float* ie, int col) {
    return (col < N_USERS) ? (ue + (size_t)col * DIM)
                           : (ie + (size_t)(col - N_USERS) * DIM);
}

// ---------------------------------------------------------------------------
// Fused score for one (u,i) pair: one wave, lane = dim. u-list and i-list
// gathers interleaved -> 8 independent 256B loads in flight per round.
// ---------------------------------------------------------------------------
__device__ __forceinline__ void score_pair(const float* __restrict__ user_emb,
                                           const float* __restrict__ item_emb,
                                           const unsigned* __restrict__ rowid,
                                           const unsigned* __restrict__ cnt,
                                           const uint2* __restrict__ pairs,
                                           const int* __restrict__ u,
                                           const int* __restrict__ it,
                                           float* __restrict__ out,
                                           int pair, int lane) {
    const unsigned uid = rowid[u[pair]];               // always assigned
    const unsigned iid = rowid[N_USERS + it[pair]];
    const unsigned un  = min(cnt[uid], (unsigned)MAXDEG);
    const unsigned in_ = min(cnt[iid], (unsigned)MAXDEG);

    uint2 ue = make_uint2(0u, 0u), ie = make_uint2(0u, 0u);
    if (lane < (int)un)  ue = pairs[(size_t)uid * MAXDEG + lane];
    if (lane < (int)in_) ie = pairs[(size_t)iid * MAXDEG + lane];

    float uacc = 0.f, iacc = 0.f;
    const unsigned rounds = un > in_ ? un : in_;

    for (unsigned j = 0; j < rounds; j += 4) {
        float mu[4], vu[4], mi[4], vi[4];
        // 4 u-gathers + 4 i-gathers issued back-to-back (all independent).
        #pragma unroll
        for (int t = 0; t < 4; ++t) {
            if (j + t < un) {                               // wave-uniform
                const int col = __shfl((int)ue.x, (int)(j + t), 64);
                vu[t] = __shfl(__uint_as_float(ue.y), (int)(j + t), 64);
                mu[t] = emb_ptr(user_emb, item_emb, col)[lane];
            }
        }
        #pragma unroll
        for (int t = 0; t < 4; ++t) {
            if (j + t < in_) {
                const int col = __shfl((int)ie.x, (int)(j + t), 64);
                vi[t] = __shfl(__uint_as_float(ie.y), (int)(j + t), 64);
                mi[t] = emb_ptr(user_emb, item_emb, col)[lane];
            }
        }
        #pragma unroll
        for (int t = 0; t < 4; ++t) if (j + t < un)  uacc += vu[t] * mu[t];
        #pragma unroll
        for (int t = 0; t < 4; ++t) if (j + t < in_) iacc += vi[t] * mi[t];
    }

    float p = uacc * iacc;
    p += __shfl_xor(p, 1);
    p += __shfl_xor(p, 2);
    p += __shfl_xor(p, 4);
    p += __shfl_xor(p, 8);
    p += __shfl_xor(p, 16);
    p += __shfl_xor(p, 32);
    if (lane == 0) out[pair] = p;
}

// ---------------------------------------------------------------------------
// Cooperative fused kernel: init -> assign -> build -> score, grid.sync()
// between phases. 1024 blocks co-resident (4/CU, 16 waves/CU at <=128 VGPR).
// ---------------------------------------------------------------------------
__global__ void __launch_bounds__(NTHR, 4)
fused_kernel(const float* __restrict__ user_emb,
             const float* __restrict__ item_emb,
             const int*   __restrict__ rows,
             const int*   __restrict__ cols,
             const float* __restrict__ vals,
             const int*   __restrict__ u,
             const int*   __restrict__ it,
             unsigned*    __restrict__ rowid,
             unsigned*    __restrict__ cnt,
             uint2*       __restrict__ pairs,
             float*       __restrict__ out) {
    cg::grid_group grid = cg::this_grid();
    const int gtid  = blockIdx.x * blockDim.x + threadIdx.x;
    const int gsize = NBLK * NTHR;                        // 262144

    // Phase 0: init tables.
    if (gtid < N_NODES) rowid[gtid] = 0xFFFFFFFFu;        // N_NODES < gsize
    if (gtid < 2 * BATCH) cnt[gtid] = 0u;
    grid.sync();

    // Phase 1: dedup-assign dense ids (atomicMin over batch entries).
    if (gtid < 2 * BATCH) {
        const int node = (gtid < BATCH) ? u[gtid] : (N_USERS + it[gtid - BATCH]);
        atomicMin(&rowid[node], (unsigned)gtid);
    }
    grid.sync();

    // Phase 2: build padded per-id edge lists (~19.5% of edges survive).
    for (int e = gtid; e < NNZ; e += gsize) {
        const unsigned id = rowid[rows[e]];               // 600KB table, L2-hot
        if (id != 0xFFFFFFFFu) {
            const unsigned slot = atomicAdd(&cnt[id], 1u);
            if (slot < MAXDEG)
                pairs[(size_t)id * MAXDEG + slot] =
                    make_uint2((unsigned)cols[e], __float_as_uint(vals[e]));
        }
    }
    grid.sync();

    // Phase 3: fused propagate+score. 4096 waves, 4 pairs each, grid-stride.
    const int lane = threadIdx.x & 63;
    const int wave = gtid >> 6;
    const int nwav = gsize >> 6;                          // 4096
    for (int pair = wave; pair < BATCH; pair += nwav)
        score_pair(user_emb, item_emb, rowid, cnt, pairs, u, it, out, pair, lane);
}

// ---------------------------------------------------------------------------
// Fallback path (proven round-8 structure) in case cooperative launch is
// rejected under graph capture. Decision is deterministic per-process.
// ---------------------------------------------------------------------------
__global__ void assign_ids_kernel(const int* __restrict__ u,
                                  const int* __restrict__ it,
                                  unsigned* __restrict__ rowid,
                                  unsigned* __restrict__ cnt) {
    const int t = blockIdx.x * blockDim.x + threadIdx.x;
    if (t >= 2 * BATCH) return;
    cnt[t] = 0u;
    const int node = (t < BATCH) ? u[t] : (N_USERS + it[t - BATCH]);
    atomicMin(&rowid[node], (unsigned)t);
}

__global__ void build_lists_kernel(const int*   __restrict__ rows,
                                   const int*   __restrict__ cols,
                                   const float* __restrict__ vals,
                                   const unsigned* __restrict__ rowid,
                                   unsigned* __restrict__ cnt,
                                   uint2* __restrict__ pairs) {
    const int e = blockIdx.x * blockDim.x + threadIdx.x;
    if (e >= NNZ) return;
    const unsigned id = rowid[rows[e]];
    if (id == 0xFFFFFFFFu) return;
    const unsigned slot = atomicAdd(&cnt[id], 1u);
    if (slot < MAXDEG)
        pairs[(size_t)id * MAXDEG + slot] =
            make_uint2((unsigned)cols[e], __float_as_uint(vals[e]));
}

__global__ void score_kernel(const float* __restrict__ user_emb,
                             const float* __restrict__ item_emb,
                             const int* __restrict__ u,
                             const int* __restrict__ it,
                             const unsigned* __restrict__ rowid,
                             const unsigned* __restrict__ cnt,
                             const uint2* __restrict__ pairs,
                             float* __restrict__ out) {
    const int lane = threadIdx.x & 63;
    const int wave = (blockIdx.x * blockDim.x + threadIdx.x) >> 6;
    if (wave >= BATCH) return;
    score_pair(user_emb, item_emb, rowid, cnt, pairs, u, it, out, wave, lane);
}

extern "C" void kernel_launch(void* const* d_in, const int* in_sizes, int n_in,
                              void* d_out, int out_size, void* d_ws, size_t ws_size,
                              hipStream_t stream) {
    const float* user_emb = (const float*)d_in[0];
    const float* item_emb = (const float*)d_in[1];
    const int*   rows     = (const int*)d_in[2];
    const int*   cols     = (const int*)d_in[3];
    const float* vals     = (const float*)d_in[4];
    const int*   u        = (const int*)d_in[5];
    const int*   it       = (const int*)d_in[6];
    float*       out      = (float*)d_out;

    unsigned* rowid = (unsigned*)d_ws;                               // 600 KB
    unsigned* cnt   = rowid + N_NODES;                               // 128 KB
    uint2*    pairs = (uint2*)(cnt + 2 * BATCH);                     // 16.8 MB

    void* kargs[] = { (void*)&user_emb, (void*)&item_emb, (void*)&rows,
                      (void*)&cols, (void*)&vals, (void*)&u, (void*)&it,
                      (void*)&rowid, (void*)&cnt, (void*)&pairs, (void*)&out };

    hipError_t err = hipLaunchCooperativeKernel((void*)fused_kernel,
                                                dim3(NBLK), dim3(NTHR),
                                                kargs, 0, stream);
    if (err != hipSuccess) {
        // Deterministic fallback: proven 4-dispatch round-8 path.
        (void)hipGetLastError();  // clear sticky error
        hipMemsetAsync(rowid, 0xFF, (size_t)N_NODES * sizeof(unsigned), stream);
        assign_ids_kernel<<<(2 * BATCH + 255) / 256, 256, 0, stream>>>(u, it, rowid, cnt);
        build_lists_kernel<<<(NNZ + 255) / 256, 256, 0, stream>>>(rows, cols, vals,
                                                                  rowid, cnt, pairs);
        score_kernel<<<(BATCH * 64) / 256, 256, 0, stream>>>(user_emb, item_emb, u, it,
                                                             rowid, cnt, pairs, out);
    }
}

// Round 14
// 130.951 us; speedup vs baseline: 3.3221x; 3.3221x over previous
//
#include <hip/hip_runtime.h>

#define N_USERS 100000
#define N_ITEMS 50000
#define N_NODES 150000   // N_USERS + N_ITEMS
#define NNZ     1200000
#define DIM     64
#define BATCH   16384
#define MAXDEG  64       // max degree over needed rows ~30 at Pois(8); writes clamped

// ws layout:
//   rowid : N_NODES uint   (memset 0xFF -> 0xFFFFFFFF = "not needed")
//   cnt   : 2*BATCH uint   (zeroed in phase A)
//   pairs : 2*BATCH*MAXDEG uint2 {col, val-bits} (written before read)

__device__ __forceinline__ const float* emb_ptr(const float* ue, const float* ie, int col) {
    return (col < N_USERS) ? (ue + (size_t)col * DIM)
                           : (ie + (size_t)(col - N_USERS) * DIM);
}

// ---------------------------------------------------------------------------
// A: dedup-assign dense ids to needed nodes; zero the per-id edge counters.
// ---------------------------------------------------------------------------
__global__ void assign_ids_kernel(const int* __restrict__ u,
                                  const int* __restrict__ it,
                                  unsigned* __restrict__ rowid,
                                  unsigned* __restrict__ cnt) {
    const int t = blockIdx.x * blockDim.x + threadIdx.x;
    if (t >= 2 * BATCH) return;
    cnt[t] = 0u;
    const int node = (t < BATCH) ? u[t] : (N_USERS + it[t - BATCH]);
    atomicMin(&rowid[node], (unsigned)t);
}

// ---------------------------------------------------------------------------
// B: build padded per-id edge lists for needed rows only (~19.5% of edges).
// ---------------------------------------------------------------------------
__global__ void build_lists_kernel(const int*   __restrict__ rows,
                                   const int*   __restrict__ cols,
                                   const float* __restrict__ vals,
                                   const unsigned* __restrict__ rowid,
                                   unsigned* __restrict__ cnt,
                                   uint2* __restrict__ pairs) {
    const int e = blockIdx.x * blockDim.x + threadIdx.x;
    if (e >= NNZ) return;
    const unsigned id = rowid[rows[e]];        // random read, 600KB table (L2-hot)
    if (id == 0xFFFFFFFFu) return;
    const unsigned slot = atomicAdd(&cnt[id], 1u);
    if (slot < MAXDEG)
        pairs[(size_t)id * MAXDEG + slot] =
            make_uint2((unsigned)cols[e], __float_as_uint(vals[e]));
}

// ---------------------------------------------------------------------------
// C: fused propagate+score, one wave per (u,i) pair, lane = dim.
// u-list and i-list gathers INTERLEAVED -> 8 independent 256B loads in
// flight per round (vs 4 in the round-8 version); serial gather rounds
// per pair drop ~2x.
// ---------------------------------------------------------------------------
__global__ void __launch_bounds__(256)
score_kernel(const float* __restrict__ user_emb,
             const float* __restrict__ item_emb,
             const int* __restrict__ u,
             const int* __restrict__ it,
             const unsigned* __restrict__ rowid,
             const unsigned* __restrict__ cnt,
             const uint2* __restrict__ pairs,
             float* __restrict__ out) {
    const int lane = threadIdx.x & 63;
    const int pair = (blockIdx.x * blockDim.x + threadIdx.x) >> 6;
    if (pair >= BATCH) return;

    const unsigned uid = rowid[u[pair]];               // always assigned
    const unsigned iid = rowid[N_USERS + it[pair]];
    const unsigned un  = min(cnt[uid], (unsigned)MAXDEG);
    const unsigned in_ = min(cnt[iid], (unsigned)MAXDEG);

    uint2 ue = make_uint2(0u, 0u), ie = make_uint2(0u, 0u);
    if (lane < (int)un)  ue = pairs[(size_t)uid * MAXDEG + lane];
    if (lane < (int)in_) ie = pairs[(size_t)iid * MAXDEG + lane];

    float uacc = 0.f, iacc = 0.f;
    const unsigned rounds = un > in_ ? un : in_;

    for (unsigned j = 0; j < rounds; j += 4) {
        float mu[4], vu[4], mi[4], vi[4];
        // 4 u-gathers + 4 i-gathers issued back-to-back (all independent,
        // wave-uniform guards -> no divergence, no wasted fetch).
        #pragma unroll
        for (int t = 0; t < 4; ++t) {
            if (j + t < un) {
                const int col = __shfl((int)ue.x, (int)(j + t), 64);
                vu[t] = __shfl(__uint_as_float(ue.y), (int)(j + t), 64);
                mu[t] = emb_ptr(user_emb, item_emb, col)[lane];
            }
        }
        #pragma unroll
        for (int t = 0; t < 4; ++t) {
            if (j + t < in_) {
                const int col = __shfl((int)ie.x, (int)(j + t), 64);
                vi[t] = __shfl(__uint_as_float(ie.y), (int)(j + t), 64);
                mi[t] = emb_ptr(user_emb, item_emb, col)[lane];
            }
        }
        #pragma unroll
        for (int t = 0; t < 4; ++t) if (j + t < un)  uacc += vu[t] * mu[t];
        #pragma unroll
        for (int t = 0; t < 4; ++t) if (j + t < in_) iacc += vi[t] * mi[t];
    }

    float p = uacc * iacc;
    p += __shfl_xor(p, 1);
    p += __shfl_xor(p, 2);
    p += __shfl_xor(p, 4);
    p += __shfl_xor(p, 8);
    p += __shfl_xor(p, 16);
    p += __shfl_xor(p, 32);
    if (lane == 0) out[pair] = p;
}

extern "C" void kernel_launch(void* const* d_in, const int* in_sizes, int n_in,
                              void* d_out, int out_size, void* d_ws, size_t ws_size,
                              hipStream_t stream) {
    const float* user_emb = (const float*)d_in[0];
    const float* item_emb = (const float*)d_in[1];
    const int*   rows     = (const int*)d_in[2];
    const int*   cols     = (const int*)d_in[3];
    const float* vals     = (const float*)d_in[4];
    const int*   u        = (const int*)d_in[5];
    const int*   it       = (const int*)d_in[6];
    float*       out      = (float*)d_out;

    unsigned* rowid = (unsigned*)d_ws;                               // 600 KB
    unsigned* cnt   = rowid + N_NODES;                               // 128 KB
    uint2*    pairs = (uint2*)(cnt + 2 * BATCH);                     // 16.8 MB

    // Only rowid needs pre-init (0xFFFFFFFF = unassigned).
    hipMemsetAsync(rowid, 0xFF, (size_t)N_NODES * sizeof(unsigned), stream);

    assign_ids_kernel<<<(2 * BATCH + 255) / 256, 256, 0, stream>>>(u, it, rowid, cnt);

    build_lists_kernel<<<(NNZ + 255) / 256, 256, 0, stream>>>(rows, cols, vals,
                                                              rowid, cnt, pairs);

    score_kernel<<<(BATCH * 64) / 256, 256, 0, stream>>>(user_emb, item_emb, u, it,
                                                         rowid, cnt, pairs, out);
}

// Round 16
// 128.512 us; speedup vs baseline: 3.3852x; 1.0190x over previous
//
#include <hip/hip_runtime.h>

#define N_USERS 100000
#define N_ITEMS 50000
#define N_NODES 150000   // N_USERS + N_ITEMS
#define NNZ     1200000
#define DIM     64
#define BATCH   16384
#define MAXDEG  64       // max degree over needed rows ~30 at Pois(8); writes clamped

// ws layout:
//   rowid : N_NODES uint   (memset 0xFF -> 0xFFFFFFFF = "not needed")
//   cnt   : 2*BATCH uint   (zeroed in phase A)
//   pairs : 2*BATCH*MAXDEG uint2 {col, val-bits} (written before read)

__device__ __forceinline__ const float* emb_ptr(const float* ue, const float* ie, int col) {
    return (col < N_USERS) ? (ue + (size_t)col * DIM)
                           : (ie + (size_t)(col - N_USERS) * DIM);
}

// ---------------------------------------------------------------------------
// A: dedup-assign dense ids to needed nodes; zero the per-id edge counters.
// ---------------------------------------------------------------------------
__global__ void assign_ids_kernel(const int* __restrict__ u,
                                  const int* __restrict__ it,
                                  unsigned* __restrict__ rowid,
                                  unsigned* __restrict__ cnt) {
    const int t = blockIdx.x * blockDim.x + threadIdx.x;
    if (t >= 2 * BATCH) return;
    cnt[t] = 0u;
    const int node = (t < BATCH) ? u[t] : (N_USERS + it[t - BATCH]);
    atomicMin(&rowid[node], (unsigned)t);
}

// ---------------------------------------------------------------------------
// B: build padded per-id edge lists for needed rows only (~19.5% of edges).
// ---------------------------------------------------------------------------
__global__ void build_lists_kernel(const int*   __restrict__ rows,
                                   const int*   __restrict__ cols,
                                   const float* __restrict__ vals,
                                   const unsigned* __restrict__ rowid,
                                   unsigned* __restrict__ cnt,
                                   uint2* __restrict__ pairs) {
    const int e = blockIdx.x * blockDim.x + threadIdx.x;
    if (e >= NNZ) return;
    const unsigned id = rowid[rows[e]];        // random read, 600KB table (L2-hot)
    if (id == 0xFFFFFFFFu) return;
    const unsigned slot = atomicAdd(&cnt[id], 1u);
    if (slot < MAXDEG)
        pairs[(size_t)id * MAXDEG + slot] =
            make_uint2((unsigned)cols[e], __float_as_uint(vals[e]));
}

// ---------------------------------------------------------------------------
// C: fused propagate+score. One wave per pair; HALF-WAVE per edge row:
// lanes 0-31 walk the u-list, lanes 32-63 the i-list, each lane holding
// dims (2*sub, 2*sub+1) as float2. One load instruction = 512B = 2 edge
// rows (vs 256B before) -> half the vector-mem instructions per pair.
// Halves stay convergent: uniform round count, per-half exec-mask guards.
// ---------------------------------------------------------------------------
__global__ void __launch_bounds__(256)
score_kernel(const float* __restrict__ user_emb,
             const float* __restrict__ item_emb,
             const int* __restrict__ u,
             const int* __restrict__ it,
             const unsigned* __restrict__ rowid,
             const unsigned* __restrict__ cnt,
             const uint2* __restrict__ pairs,
             float* __restrict__ out) {
    const int lane = threadIdx.x & 63;
    const int sub  = lane & 31;
    const bool hi  = lane >= 32;
    const int base = hi ? 32 : 0;
    const int pair = (blockIdx.x * blockDim.x + threadIdx.x) >> 6;
    if (pair >= BATCH) return;

    // Each half resolves its own list (predicated loads, no branch).
    const int node     = hi ? (N_USERS + it[pair]) : u[pair];
    const unsigned id  = rowid[node];                     // always assigned
    const unsigned n   = min(cnt[id], (unsigned)MAXDEG);

    // Stage this half's list entries across its 32 lanes (2 deep covers 64).
    uint2 e0 = make_uint2(0u, 0u), e1 = make_uint2(0u, 0u);
    if (sub < (int)n)        e0 = pairs[(size_t)id * MAXDEG + sub];
    if (sub + 32 < (int)n)   e1 = pairs[(size_t)id * MAXDEG + sub + 32];

    // Wave-uniform round count = max of the two halves' list lengths.
    const unsigned n_lo = __shfl(n, 0, 64);
    const unsigned n_hi = __shfl(n, 32, 64);
    const unsigned rounds = n_lo > n_hi ? n_lo : n_hi;

    float2 acc = make_float2(0.f, 0.f);

    for (unsigned j = 0; j < rounds; j += 4) {
        float2 m[4];
        float  vv[4];
        // 4 load instructions, each fetching TWO edge rows (one per half).
        #pragma unroll
        for (int t = 0; t < 4; ++t) {
            const unsigned k = j + t;                    // uniform
            if (k < n) {                                 // per-half exec mask
                const uint2 ent = (k < 32) ? e0 : e1;    // uniform select
                const int   src = base + (int)(k & 31);  // broadcast within half
                const int   col = __shfl((int)ent.x, src, 64);
                vv[t] = __shfl(__uint_as_float(ent.y), src, 64);
                m[t] = *(const float2*)(emb_ptr(user_emb, item_emb, col) + 2 * sub);
            }
        }
        #pragma unroll
        for (int t = 0; t < 4; ++t) {
            if (j + t < n) {
                acc.x += vv[t] * m[t].x;
                acc.y += vv[t] * m[t].y;
            }
        }
    }

    // acc (low half) = u-prop dims (2sub,2sub+1); (high half) = i-prop dims.
    float2 other;
    other.x = __shfl_xor(acc.x, 32, 64);
    other.y = __shfl_xor(acc.y, 32, 64);
    float p = acc.x * other.x + acc.y * other.y;

    p += __shfl_xor(p, 1);
    p += __shfl_xor(p, 2);
    p += __shfl_xor(p, 4);
    p += __shfl_xor(p, 8);
    p += __shfl_xor(p, 16);

    if (lane == 0) out[pair] = p;
}

extern "C" void kernel_launch(void* const* d_in, const int* in_sizes, int n_in,
                              void* d_out, int out_size, void* d_ws, size_t ws_size,
                              hipStream_t stream) {
    const float* user_emb = (const float*)d_in[0];
    const float* item_emb = (const float*)d_in[1];
    const int*   rows     = (const int*)d_in[2];
    const int*   cols     = (const int*)d_in[3];
    const float* vals     = (const float*)d_in[4];
    const int*   u        = (const int*)d_in[5];
    const int*   it       = (const int*)d_in[6];
    float*       out      = (float*)d_out;

    unsigned* rowid = (unsigned*)d_ws;                               // 600 KB
    unsigned* cnt   = rowid + N_NODES;                               // 128 KB
    uint2*    pairs = (uint2*)(cnt + 2 * BATCH);                     // 16.8 MB

    // Only rowid needs pre-init (0xFFFFFFFF = unassigned).
    hipMemsetAsync(rowid, 0xFF, (size_t)N_NODES * sizeof(unsigned), stream);

    assign_ids_kernel<<<(2 * BATCH + 255) / 256, 256, 0, stream>>>(u, it, rowid, cnt);

    build_lists_kernel<<<(NNZ + 255) / 256, 256, 0, stream>>>(rows, cols, vals,
                                                              rowid, cnt, pairs);

    score_kernel<<<(BATCH * 64) / 256, 256, 0, stream>>>(user_emb, item_emb, u, it,
                                                         rowid, cnt, pairs, out);
}